// Round 8
// baseline (690.081 us; speedup 1.0000x reference)
//
#include <hip/hip_runtime.h>
#include <cmath>

namespace {

constexpr int B = 16, C = 3, H = 768, W = 768;
constexpr int HW = H * W;
constexpr int BC = B * C;
constexpr int NDROPS = 10;
constexpr int KS[NDROPS] = {23, 37, 13, 23, 13, 33, 25, 27, 15, 21};
constexpr float BLUR_R[NDROPS] = {11.3535f, 17.9381f, 5.7966f, 10.8586f, 5.5301f,
                                  15.9075f, 12.3225f, 13.4871f, 6.6639f, 9.5413f};
constexpr int MAXK = 37;
constexpr int MAXP = MAXK / 2;  // 18

// mask < ~8.6e-8 outside d > SFAC^2 (d^1.8 > 16.2): composite == prev there.
constexpr float SFAC = 2.17f;
constexpr int BOXW = 384;           // >= 2*2.17*80 = 348 (covers clamp cases)
constexpr int BOXH = 288;           // >= 2*2.17*64 = 278
constexpr int YT = 32;              // output rows per fused tile
constexpr int MH = BOXH + 2 * MAXP; // 324  (mask box rows, reflect baked in)
constexpr int MW = 448;             // mask box cols (covers box +/- MAXP)

struct TapW {
    float w[MAXK];
};

}  // namespace

__device__ inline int refl(int v, int n) {
    return v < 0 ? -v : (v >= n ? 2 * n - 2 - v : v);
}

__device__ inline void drop_params(const float* __restrict__ pos,
                                   const float* __restrict__ rad, int j,
                                   float& x0, float& y0, float& wr, float& hr) {
    float px = fminf(fmaxf(pos[2 * j + 0], -1.f), 1.f);
    float py = fminf(fmaxf(pos[2 * j + 1], -1.f), 1.f);
    wr = fminf(fmaxf(rad[j], 60.f), 80.f);
    x0 = (px + 1.f) * 0.5f * (float)W;
    y0 = (py + 1.f) * 0.5f * (float)H;
    hr = wr * 0.8f;
}

__device__ inline void drop_box(const float* __restrict__ pos,
                                const float* __restrict__ rad, int j,
                                int& bx0, int& by0) {
    float x0, y0, wr, hr;
    drop_params(pos, rad, j, x0, y0, wr, hr);
    bx0 = max(0, (int)floorf(x0 - SFAC * wr));
    by0 = max(0, (int)floorf(y0 - SFAC * hr));
}

// ---------------------------------------------------------------------------
// Compact per-drop masks with reflection baked in:
// mbox[j][yi][xi] = mask_plane[refl(by0-MAXP+yi)][refl(bx0-MAXP+xi)]
// Only 10*324*448 = 1.45M powf/expf evals (vs 59M full-plane).
// ---------------------------------------------------------------------------
__global__ void maskbox_kernel(const float* __restrict__ pos,
                               const float* __restrict__ rad,
                               float* __restrict__ mbox) {
    int j = blockIdx.y;
    int idx = blockIdx.x * 256 + threadIdx.x;
    if (idx >= MH * MW) return;
    int yi = idx / MW;
    int xi = idx - yi * MW;
    int bx0, by0;
    drop_box(pos, rad, j, bx0, by0);
    float x0, y0, wr, hr;
    drop_params(pos, rad, j, x0, y0, wr, hr);
    int rx = refl(bx0 - MAXP + xi, W);
    int ry = refl(by0 - MAXP + yi, H);
    float dy = (float)ry - y0;
    float dx = (float)rx - x0;
    float d = dy * dy / (hr * hr) + dx * dx / (wr * wr);
    float m = expf(-powf(d, 1.8f) + 1e-10f);
    m = fminf(fmaxf(m, 0.f), 1.f);
    mbox[(size_t)j * MH * MW + idx] = m;
}

__global__ void copy_kernel(const float4* __restrict__ src,
                            float4* __restrict__ dst, int n) {
    int i = blockIdx.x * blockDim.x + threadIdx.x;
    if (i < n) dst[i] = src[i];
}

// ---------------------------------------------------------------------------
// Fully-fused per-drop blur: product+V-blur+H-blur through two LDS tiles.
// Reads `out` (previous state, read-only here) and writes the blurred box
// into compact `stage` (race-free; composite applied by composite_kernel).
// Block: (64,4). Tile: 64 output cols x YT=32 output rows.
//   Phase A: prod[r][c] = out[refl]*mbox  (reflect once per pixel)
//   Phase B: vbl = V-blur(prod), b64 reads, 2 cols x 8-row sliding coarsen
//   Phase C: stage = H-blur(vbl), 8-col sliding coarsen, float4 stores
// ---------------------------------------------------------------------------
template <int K>
__global__ __launch_bounds__(256) void fusedDrop(
    const float* __restrict__ out, const float* __restrict__ mbox,
    float* __restrict__ stage, const float* __restrict__ pos,
    const float* __restrict__ rad, int j, TapW tw) {
    constexpr int P = K / 2;
    constexpr int TC = 64 + K - 1;   // prod/vbl cols (even, K odd)
    constexpr int TR = YT + K - 1;   // prod rows
    constexpr int PC = TC + 2;       // prod row stride (even, 8B-aligned rows)
    constexpr int VC = TC + 1;       // vbl row stride (odd -> bank spread)
    __shared__ float prod[TR][PC];
    __shared__ float vbl[YT][VC];

    int bx0, by0;
    drop_box(pos, rad, j, bx0, by0);
    int tx = threadIdx.x, ty = threadIdx.y;
    int xb = blockIdx.x * 64;   // block's first output col (box space)
    int yb = blockIdx.y * YT;   // block's first output row (box space)
    int bc = blockIdx.z;
    const float* mb = mbox + (size_t)j * MH * MW;
    const float* op = out + (size_t)bc * HW;

    // Phase A: masked product tile (reflect + mask lookup once per pixel)
    for (int cc = tx; cc < TC; cc += 64) {
        int rx = refl(bx0 + xb - P + cc, W);
        int xim = xb + cc + (MAXP - P);
        for (int r = ty; r < TR; r += 4) {
            int ry = refl(by0 + yb - P + r, H);
            prod[r][cc] = op[ry * W + rx] * mb[(yb + r + (MAXP - P)) * MW + xim];
        }
    }
    __syncthreads();

    // Phase B: vertical blur. Each thread: cols (2tx, 2tx+1), rows base..base+7.
    {
        int c0 = 2 * tx;
        int base = ty * 8;
        if (c0 < TC) {
            float a0[8] = {0, 0, 0, 0, 0, 0, 0, 0};
            float a1[8] = {0, 0, 0, 0, 0, 0, 0, 0};
#pragma unroll
            for (int t = 0; t < K + 7; ++t) {
                float2 v = *(const float2*)&prod[base + t][c0];
#pragma unroll
                for (int o = 0; o < 8; ++o) {
                    int ti = t - o;
                    if (ti >= 0 && ti < K) {
                        a0[o] += tw.w[ti] * v.x;
                        a1[o] += tw.w[ti] * v.y;
                    }
                }
            }
#pragma unroll
            for (int o = 0; o < 8; ++o) {
                vbl[base + o][c0] = a0[o];
                vbl[base + o][c0 + 1] = a1[o];
            }
        }
    }
    __syncthreads();

    // Phase C: horizontal blur, 8 consecutive cols per thread, sliding reads.
    {
        int tid = ty * 64 + tx;
        int xq = (tid & 7) * 8;  // 0,8,...,56
        int yi = tid >> 3;       // 0..31
        float acc[8] = {0, 0, 0, 0, 0, 0, 0, 0};
#pragma unroll
        for (int t = 0; t < K + 7; ++t) {
            float v = vbl[yi][xq + t];
#pragma unroll
            for (int o = 0; o < 8; ++o) {
                int ti = t - o;
                if (ti >= 0 && ti < K) acc[o] += tw.w[ti] * v;
            }
        }
        float* srow = stage + ((size_t)bc * BOXH + (yb + yi)) * BOXW + (xb + xq);
        *(float4*)&srow[0] = make_float4(acc[0], acc[1], acc[2], acc[3]);
        *(float4*)&srow[4] = make_float4(acc[4], acc[5], acc[6], acc[7]);
    }
}

// ---------------------------------------------------------------------------
// Composite: out = stage*m + out*(1-m) over the box (own-pixel RMW, race-free).
// ---------------------------------------------------------------------------
__global__ __launch_bounds__(256) void composite_kernel(
    const float* __restrict__ stage, const float* __restrict__ mbox,
    float* __restrict__ out, const float* __restrict__ pos,
    const float* __restrict__ rad, int j) {
    int bx0, by0;
    drop_box(pos, rad, j, bx0, by0);
    int ci = blockIdx.x * 64 + threadIdx.x;  // [0, BOXW)
    int yi = blockIdx.y * 4 + threadIdx.y;   // [0, BOXH)
    int bc = blockIdx.z;
    int x = bx0 + ci;
    int y = by0 + yi;
    if (x >= W || y >= H) return;
    float m = mbox[(size_t)j * MH * MW + (size_t)(yi + MAXP) * MW + (ci + MAXP)];
    float s = stage[((size_t)bc * BOXH + yi) * BOXW + ci];
    size_t o = (size_t)bc * HW + (size_t)y * W + x;
    out[o] = s * m + out[o] * (1.f - m);
}

// ---------------------------------------------------------------------------
// Host side
// ---------------------------------------------------------------------------
static void make_weights(int j, TapW& tw) {
    int K = KS[j];
    float sigma = BLUR_R[j];
    float half = (K - 1) * 0.5f;
    float sum = 0.f;
    for (int i = 0; i < K; ++i) {
        float xx = -half + (float)i;
        float v = xx / sigma;
        float p = expf(-0.5f * v * v);
        tw.w[i] = p;
        sum += p;
    }
    for (int i = 0; i < K; ++i) tw.w[i] /= sum;
    for (int i = K; i < MAXK; ++i) tw.w[i] = 0.f;
}

template <int K>
static void launch_fused(hipStream_t stream, const float* out,
                         const float* mbox, float* stage, const float* pos,
                         const float* rad, int j, const TapW& tw) {
    dim3 blk(64, 4, 1);
    dim3 grid(BOXW / 64, BOXH / YT, BC);  // 6 x 9 x 48
    fusedDrop<K><<<grid, blk, 0, stream>>>(out, mbox, stage, pos, rad, j, tw);
}

static void launch_drop(int K, hipStream_t stream, float* out,
                        const float* mbox, float* stage, const float* pos,
                        const float* rad, int j, const TapW& tw) {
    switch (K) {
        case 13: launch_fused<13>(stream, out, mbox, stage, pos, rad, j, tw); break;
        case 15: launch_fused<15>(stream, out, mbox, stage, pos, rad, j, tw); break;
        case 21: launch_fused<21>(stream, out, mbox, stage, pos, rad, j, tw); break;
        case 23: launch_fused<23>(stream, out, mbox, stage, pos, rad, j, tw); break;
        case 25: launch_fused<25>(stream, out, mbox, stage, pos, rad, j, tw); break;
        case 27: launch_fused<27>(stream, out, mbox, stage, pos, rad, j, tw); break;
        case 33: launch_fused<33>(stream, out, mbox, stage, pos, rad, j, tw); break;
        case 37: launch_fused<37>(stream, out, mbox, stage, pos, rad, j, tw); break;
    }
    dim3 blk(64, 4, 1);
    dim3 grid(BOXW / 64, BOXH / 4, BC);  // 6 x 72 x 48
    composite_kernel<<<grid, blk, 0, stream>>>(stage, mbox, out, pos, rad, j);
}

extern "C" void kernel_launch(void* const* d_in, const int* in_sizes, int n_in,
                              void* d_out, int out_size, void* d_ws,
                              size_t ws_size, hipStream_t stream) {
    const float* img = (const float*)d_in[0];
    const float* pos = (const float*)d_in[1];
    const float* rad = (const float*)d_in[2];
    float* out = (float*)d_out;

    // ws: [mbox: 10*MH*MW f32 = 5.8MB][stage: BC*BOXH*BOXW f32 = 21.2MB]
    float* mbox = (float*)d_ws;
    float* stage = mbox + (size_t)NDROPS * MH * MW;

    maskbox_kernel<<<dim3((MH * MW + 255) / 256, NDROPS), 256, 0, stream>>>(
        pos, rad, mbox);
    copy_kernel<<<(BC * HW / 4 + 255) / 256, 256, 0, stream>>>(
        (const float4*)img, (float4*)out, BC * HW / 4);

    for (int j = 0; j < NDROPS; ++j) {
        TapW tw;
        make_weights(j, tw);
        launch_drop(KS[j], stream, out, mbox, stage, pos, rad, j, tw);
    }
}